// Round 1
// baseline (1085.787 us; speedup 1.0000x reference)
//
#include <hip/hip_runtime.h>
#include <hip/hip_bf16.h>

#define C 256
#define BM 64
#define BN 64
#define BK 16

// ---------------- GEMM1: acw[N][256] = A[N][256] @ W_w[256][256] + b_w (bf16 out) ----------------
__global__ void k_gemm_acw(const float* __restrict__ A, const float* __restrict__ W,
                           const float* __restrict__ bias, __hip_bfloat16* __restrict__ acw,
                           int N) {
    __shared__ float As[BK][BM + 1];
    __shared__ float Bs[BK][BN];
    const int col0 = blockIdx.x * BN;
    const int row0 = blockIdx.y * BM;
    const int tid = threadIdx.x;
    const int tx = tid & 15, ty = tid >> 4;
    const int lr = tid >> 2;            // 0..63 : A-load row within tile
    const int lkq = (tid & 3) * 4;      // 0,4,8,12 : A-load k quad
    const int wk = tid >> 4;            // 0..15 : W-load k
    const int wc = (tid & 15) * 4;      // W-load col quad
    const int grA = row0 + lr;
    const bool okA = grA < N;

    float acc[4][4] = {};

    for (int kk = 0; kk < C; kk += BK) {
        float4 a = okA ? *(const float4*)(A + (size_t)grA * C + kk + lkq)
                       : make_float4(0.f, 0.f, 0.f, 0.f);
        As[lkq + 0][lr] = a.x;
        As[lkq + 1][lr] = a.y;
        As[lkq + 2][lr] = a.z;
        As[lkq + 3][lr] = a.w;
        *(float4*)&Bs[wk][wc] = *(const float4*)(W + (size_t)(kk + wk) * C + col0 + wc);
        __syncthreads();
#pragma unroll
        for (int k = 0; k < BK; ++k) {
            float av[4], bv[4];
#pragma unroll
            for (int i = 0; i < 4; ++i) av[i] = As[k][ty * 4 + i];
#pragma unroll
            for (int j = 0; j < 4; ++j) bv[j] = Bs[k][tx * 4 + j];
#pragma unroll
            for (int i = 0; i < 4; ++i)
#pragma unroll
                for (int j = 0; j < 4; ++j) acc[i][j] += av[i] * bv[j];
        }
        __syncthreads();
    }

#pragma unroll
    for (int i = 0; i < 4; ++i) {
        int gr = row0 + ty * 4 + i;
        if (gr < N) {
            int gc0 = col0 + tx * 4;
            __hip_bfloat16 h[4];
#pragma unroll
            for (int j = 0; j < 4; ++j) h[j] = __float2bfloat16(acc[i][j] + bias[gc0 + j]);
            *(ushort4*)(acw + (size_t)gr * C + gc0) = *(const ushort4*)h;
        }
    }
}

// ---------------- CSR build ----------------
__global__ void k_count(const int* __restrict__ index1, unsigned* __restrict__ count, int E) {
    int e = blockIdx.x * blockDim.x + threadIdx.x;
    if (e < E) atomicAdd(&count[index1[e]], 1u);
}

// single-block exclusive scan over V elements (Hillis-Steele on 1024-chunks with carry)
__global__ void k_scan(const unsigned* __restrict__ count, unsigned* __restrict__ offsets, int V) {
    __shared__ unsigned s[1024];
    __shared__ unsigned carry;
    const int tid = threadIdx.x;
    if (tid == 0) carry = 0;
    __syncthreads();
    for (int base = 0; base < V; base += 1024) {
        int i = base + tid;
        unsigned x = (i < V) ? count[i] : 0u;
        s[tid] = x;
        __syncthreads();
        for (int off = 1; off < 1024; off <<= 1) {
            unsigned t = (tid >= off) ? s[tid - off] : 0u;
            __syncthreads();
            s[tid] += t;
            __syncthreads();
        }
        unsigned incl = s[tid];
        if (i < V) offsets[i] = carry + (incl - x);
        __syncthreads();
        if (tid == 1023) carry += s[1023];
        __syncthreads();
    }
    if (tid == 0) offsets[V] = carry;
}

__global__ void k_fill(const int* __restrict__ index1, const unsigned* __restrict__ offsets,
                       unsigned* __restrict__ cursor, unsigned* __restrict__ edge_ids, int E) {
    int e = blockIdx.x * blockDim.x + threadIdx.x;
    if (e < E) {
        int v = index1[e];
        unsigned pos = atomicAdd(&cursor[v], 1u);
        edge_ids[offsets[v] + pos] = (unsigned)e;
    }
}

// ---------------- per-node aggregation: out[v][:] = sum_e w*acw[nbr[e]][:], deg[v] = sum_e w ----------------
__global__ void k_aggr(const unsigned* __restrict__ offsets, const unsigned* __restrict__ edge_ids,
                       const float* __restrict__ ew, const int* __restrict__ nbr,
                       const __hip_bfloat16* __restrict__ acw,
                       float* __restrict__ out, float* __restrict__ deg) {
    const int v = blockIdx.x;
    const int c = threadIdx.x;
    const unsigned beg = offsets[v], end = offsets[v + 1];
    float acc = 0.f, dsum = 0.f;
    for (unsigned i = beg; i < end; ++i) {
        unsigned e = edge_ids[i];
        float w = ew[e];
        int s = nbr[e];
        acc += w * __bfloat162float(acw[(size_t)s * C + c]);
        dsum += w;
    }
    out[(size_t)v * C + c] = acc;
    if (c == 0) deg[v] = dsum;
}

// ---------------- GEMM2 (dual-B, gathered rows, fused epilogue) ----------------
// out[v][:] += deg[v]*(nce@W1 + b1) + nce@W2 + b2, nce = A[valid_nodes[v]]
__global__ void k_gemm_final(const float* __restrict__ A, const int* __restrict__ vnodes,
                             const float* __restrict__ W1, const float* __restrict__ b1v,
                             const float* __restrict__ W2, const float* __restrict__ b2v,
                             const float* __restrict__ deg, float* __restrict__ out, int V) {
    __shared__ float As[BK][BM + 1];
    __shared__ float B1s[BK][BN];
    __shared__ float B2s[BK][BN];
    const int col0 = blockIdx.x * BN;
    const int row0 = blockIdx.y * BM;
    const int tid = threadIdx.x;
    const int tx = tid & 15, ty = tid >> 4;
    const int lr = tid >> 2;
    const int lkq = (tid & 3) * 4;
    const int wk = tid >> 4;
    const int wc = (tid & 15) * 4;
    const int vrow = row0 + lr;
    const int grA = (vrow < V) ? vnodes[vrow] : -1;

    float acc1[4][4] = {}, acc2[4][4] = {};

    for (int kk = 0; kk < C; kk += BK) {
        float4 a = (grA >= 0) ? *(const float4*)(A + (size_t)grA * C + kk + lkq)
                              : make_float4(0.f, 0.f, 0.f, 0.f);
        As[lkq + 0][lr] = a.x;
        As[lkq + 1][lr] = a.y;
        As[lkq + 2][lr] = a.z;
        As[lkq + 3][lr] = a.w;
        *(float4*)&B1s[wk][wc] = *(const float4*)(W1 + (size_t)(kk + wk) * C + col0 + wc);
        *(float4*)&B2s[wk][wc] = *(const float4*)(W2 + (size_t)(kk + wk) * C + col0 + wc);
        __syncthreads();
#pragma unroll
        for (int k = 0; k < BK; ++k) {
            float av[4], c1[4], c2[4];
#pragma unroll
            for (int i = 0; i < 4; ++i) av[i] = As[k][ty * 4 + i];
#pragma unroll
            for (int j = 0; j < 4; ++j) c1[j] = B1s[k][tx * 4 + j];
#pragma unroll
            for (int j = 0; j < 4; ++j) c2[j] = B2s[k][tx * 4 + j];
#pragma unroll
            for (int i = 0; i < 4; ++i)
#pragma unroll
                for (int j = 0; j < 4; ++j) {
                    acc1[i][j] += av[i] * c1[j];
                    acc2[i][j] += av[i] * c2[j];
                }
        }
        __syncthreads();
    }

#pragma unroll
    for (int i = 0; i < 4; ++i) {
        int vr = row0 + ty * 4 + i;
        if (vr < V) {
            float d = deg[vr];
            int gc0 = col0 + tx * 4;
            size_t o0 = (size_t)vr * C + gc0;
            float4 ag = *(const float4*)(out + o0);
            float4 bb1 = *(const float4*)(b1v + gc0);
            float4 bb2 = *(const float4*)(b2v + gc0);
            float4 r;
            r.x = ag.x + d * (acc1[i][0] + bb1.x) + acc2[i][0] + bb2.x;
            r.y = ag.y + d * (acc1[i][1] + bb1.y) + acc2[i][1] + bb2.y;
            r.z = ag.z + d * (acc1[i][2] + bb1.z) + acc2[i][2] + bb2.z;
            r.w = ag.w + d * (acc1[i][3] + bb1.w) + acc2[i][3] + bb2.w;
            *(float4*)(out + o0) = r;
        }
    }
}

extern "C" void kernel_launch(void* const* d_in, const int* in_sizes, int n_in,
                              void* d_out, int out_size, void* d_ws, size_t ws_size,
                              hipStream_t stream) {
    const float* A      = (const float*)d_in[0];
    const int* vnodes   = (const int*)d_in[2];
    const int* index1   = (const int*)d_in[4];
    const int* nbr      = (const int*)d_in[5];
    const float* ew     = (const float*)d_in[9];
    const float* W_w    = (const float*)d_in[10];
    const float* b_w    = (const float*)d_in[11];
    const float* W1     = (const float*)d_in[12];
    const float* b1     = (const float*)d_in[13];
    const float* W2     = (const float*)d_in[14];
    const float* b2     = (const float*)d_in[15];
    float* out = (float*)d_out;

    const int N = in_sizes[0] / C;
    const int V = in_sizes[2];
    const int E = in_sizes[4];

    char* ws = (char*)d_ws;
    size_t off = 0;
    auto carve = [&](size_t bytes) -> void* {
        void* p = ws + off;
        off = (off + bytes + 255) & ~(size_t)255;
        return p;
    };
    __hip_bfloat16* acw = (__hip_bfloat16*)carve((size_t)N * C * sizeof(__hip_bfloat16));
    float* deg          = (float*)carve((size_t)V * sizeof(float));
    unsigned* count     = (unsigned*)carve((size_t)V * sizeof(unsigned));
    unsigned* offsets   = (unsigned*)carve((size_t)(V + 1) * sizeof(unsigned));
    unsigned* cursor    = (unsigned*)carve((size_t)V * sizeof(unsigned));
    unsigned* edge_ids  = (unsigned*)carve((size_t)E * sizeof(unsigned));

    hipMemsetAsync(count, 0, (size_t)V * sizeof(unsigned), stream);
    hipMemsetAsync(cursor, 0, (size_t)V * sizeof(unsigned), stream);

    k_gemm_acw<<<dim3(C / BN, (N + BM - 1) / BM), 256, 0, stream>>>(A, W_w, b_w, acw, N);
    k_count<<<(E + 255) / 256, 256, 0, stream>>>(index1, count, E);
    k_scan<<<1, 1024, 0, stream>>>(count, offsets, V);
    k_fill<<<(E + 255) / 256, 256, 0, stream>>>(index1, offsets, cursor, edge_ids, E);
    k_aggr<<<V, C, 0, stream>>>(offsets, edge_ids, ew, nbr, acw, out, deg);
    k_gemm_final<<<dim3(C / BN, (V + BM - 1) / BM), 256, 0, stream>>>(A, vnodes, W1, b1, W2, b2, deg, out, V);
}

// Round 2
// 680.198 us; speedup vs baseline: 1.5963x; 1.5963x over previous
//
#include <hip/hip_runtime.h>
#include <hip/hip_bf16.h>

#define C 256

typedef __attribute__((ext_vector_type(8))) short bf16x8;
typedef __attribute__((ext_vector_type(4))) float f32x4;

__device__ __forceinline__ ushort f2bf(float x) {
    unsigned u = __float_as_uint(x);
    unsigned r = (u + 0x7fffu + ((u >> 16) & 1u)) >> 16;
    return (ushort)r;
}
__device__ __forceinline__ float bf2f(ushort u) {
    return __uint_as_float((unsigned)u << 16);
}
__device__ __forceinline__ unsigned pack2(float lo, float hi) {
    return (unsigned)f2bf(lo) | ((unsigned)f2bf(hi) << 16);
}

// ---------- cast A [M*256] f32 -> bf16 ----------
__global__ void k_cast_a(const float* __restrict__ A, ushort* __restrict__ Ab, int n8) {
    int i = blockIdx.x * blockDim.x + threadIdx.x;
    if (i >= n8) return;
    const float4* p = (const float4*)(A + (size_t)i * 8);
    float4 a = p[0], b = p[1];
    uint4 o;
    o.x = pack2(a.x, a.y);
    o.y = pack2(a.z, a.w);
    o.z = pack2(b.x, b.y);
    o.w = pack2(b.z, b.w);
    *(uint4*)(Ab + (size_t)i * 8) = o;
}

// ---------- transpose+cast 3 weight matrices: Wt[n][k] = bf16(W[k][n]) ----------
__global__ void k_cast_wt(const float* __restrict__ W0, ushort* __restrict__ T0,
                          const float* __restrict__ W1, ushort* __restrict__ T1,
                          const float* __restrict__ W2, ushort* __restrict__ T2) {
    int t = blockIdx.x * blockDim.x + threadIdx.x;
    int which = t >> 16;
    int r = t & 65535;
    int k = r & 255, n = r >> 8;
    const float* W = (which == 0) ? W0 : (which == 1) ? W1 : W2;
    ushort* T = (which == 0) ? T0 : (which == 1) ? T1 : T2;
    T[(size_t)n * C + k] = f2bf(W[(size_t)k * C + n]);
}

// ---------- MFMA GEMM1: acw[M][256] = bf16( Ab @ W ) + bias, bf16 out ----------
__global__ __launch_bounds__(256, 2)
void k_gemm_acw(const ushort* __restrict__ Ab, const ushort* __restrict__ Wt,
                const float* __restrict__ bias, ushort* __restrict__ acw, int M) {
    __shared__ __align__(16) ushort Al[128][40];
    __shared__ __align__(16) ushort Bl[128][40];
    const int tid = threadIdx.x;
    const int row0 = blockIdx.y * 128, col0 = blockIdx.x * 128;
    const int lane = tid & 63, wv = tid >> 6;
    const int wr = wv >> 1, wc = wv & 1;

    f32x4 acc[4][4] = {};

    int arow[2];
#pragma unroll
    for (int i = 0; i < 2; ++i) {
        int idx = tid + 256 * i;
        arow[i] = row0 + (idx >> 2);
    }

    for (int k0 = 0; k0 < C; k0 += 32) {
#pragma unroll
        for (int i = 0; i < 2; ++i) {
            int idx = tid + 256 * i;
            int r = idx >> 2, ch = idx & 3;
            uint4 va = (arow[i] < M) ? *(const uint4*)(Ab + (size_t)arow[i] * C + k0 + ch * 8)
                                     : make_uint4(0, 0, 0, 0);
            *(uint4*)&Al[r][ch * 8] = va;
            *(uint4*)&Bl[r][ch * 8] = *(const uint4*)(Wt + (size_t)(col0 + r) * C + k0 + ch * 8);
        }
        __syncthreads();
        bf16x8 af[4], bfr[4];
        const int kc = (lane >> 4) * 8;
#pragma unroll
        for (int m = 0; m < 4; ++m) af[m] = *(const bf16x8*)&Al[wr * 64 + m * 16 + (lane & 15)][kc];
#pragma unroll
        for (int n = 0; n < 4; ++n) bfr[n] = *(const bf16x8*)&Bl[wc * 64 + n * 16 + (lane & 15)][kc];
#pragma unroll
        for (int m = 0; m < 4; ++m)
#pragma unroll
            for (int n = 0; n < 4; ++n)
                acc[m][n] = __builtin_amdgcn_mfma_f32_16x16x32_bf16(af[m], bfr[n], acc[m][n], 0, 0, 0);
        __syncthreads();
    }

#pragma unroll
    for (int m = 0; m < 4; ++m) {
        int rbase = row0 + wr * 64 + m * 16 + (lane >> 4) * 4;
#pragma unroll
        for (int n = 0; n < 4; ++n) {
            int col = col0 + wc * 64 + n * 16 + (lane & 15);
            float bc = bias[col];
#pragma unroll
            for (int r = 0; r < 4; ++r) {
                int gr = rbase + r;
                if (gr < M) acw[(size_t)gr * C + col] = f2bf(acc[m][n][r] + bc);
            }
        }
    }
}

// ---------- CSR build ----------
__global__ void k_count(const int* __restrict__ index1, unsigned* __restrict__ count, int E) {
    int e = blockIdx.x * blockDim.x + threadIdx.x;
    if (e < E) atomicAdd(&count[index1[e]], 1u);
}

// 3-phase single-block exclusive scan
__global__ void k_scan(const unsigned* __restrict__ count, unsigned* __restrict__ offsets, int V) {
    __shared__ unsigned ws[1024];
    const int tid = threadIdx.x;
    const int per = (V + 1023) >> 10;
    const int s0 = tid * per;
    unsigned sum = 0;
    for (int j = 0; j < per; ++j) {
        int i = s0 + j;
        if (i < V) sum += count[i];
    }
    ws[tid] = sum;
    __syncthreads();
    for (int off = 1; off < 1024; off <<= 1) {
        unsigned t = (tid >= off) ? ws[tid - off] : 0u;
        __syncthreads();
        ws[tid] += t;
        __syncthreads();
    }
    unsigned run = ws[tid] - sum;
    for (int j = 0; j < per; ++j) {
        int i = s0 + j;
        if (i < V) {
            offsets[i] = run;
            run += count[i];
        }
    }
    if (tid == 1023) offsets[V] = ws[1023];
}

__global__ void k_fill(const int* __restrict__ index1, const unsigned* __restrict__ offsets,
                       unsigned* __restrict__ cursor, unsigned* __restrict__ edge_ids, int E) {
    int e = blockIdx.x * blockDim.x + threadIdx.x;
    if (e < E) {
        int v = index1[e];
        unsigned pos = atomicAdd(&cursor[v], 1u);
        edge_ids[offsets[v] + pos] = (unsigned)e;
    }
}

// ---------- aggregation: wave per node, lane holds 4 channels, 4 edges in flight ----------
__global__ void k_aggr(const unsigned* __restrict__ offsets, const unsigned* __restrict__ eids,
                       const float* __restrict__ ew, const int* __restrict__ nbr,
                       const ushort* __restrict__ acw, float* __restrict__ out,
                       float* __restrict__ deg, int V) {
    const int v = (blockIdx.x * blockDim.x + threadIdx.x) >> 6;
    const int lane = threadIdx.x & 63;
    if (v >= V) return;
    const unsigned beg = offsets[v], end = offsets[v + 1];
    const int cb = lane * 4;
    float a0 = 0.f, a1 = 0.f, a2 = 0.f, a3 = 0.f, ds = 0.f;
    unsigned i = beg;
    for (; i + 4 <= end; i += 4) {
        unsigned e0 = eids[i], e1 = eids[i + 1], e2 = eids[i + 2], e3 = eids[i + 3];
        float w0 = ew[e0], w1 = ew[e1], w2 = ew[e2], w3 = ew[e3];
        int s0 = nbr[e0], s1 = nbr[e1], s2 = nbr[e2], s3 = nbr[e3];
        ushort4 r0 = *(const ushort4*)(acw + (size_t)s0 * C + cb);
        ushort4 r1 = *(const ushort4*)(acw + (size_t)s1 * C + cb);
        ushort4 r2 = *(const ushort4*)(acw + (size_t)s2 * C + cb);
        ushort4 r3 = *(const ushort4*)(acw + (size_t)s3 * C + cb);
        a0 += w0 * bf2f(r0.x) + w1 * bf2f(r1.x) + w2 * bf2f(r2.x) + w3 * bf2f(r3.x);
        a1 += w0 * bf2f(r0.y) + w1 * bf2f(r1.y) + w2 * bf2f(r2.y) + w3 * bf2f(r3.y);
        a2 += w0 * bf2f(r0.z) + w1 * bf2f(r1.z) + w2 * bf2f(r2.z) + w3 * bf2f(r3.z);
        a3 += w0 * bf2f(r0.w) + w1 * bf2f(r1.w) + w2 * bf2f(r2.w) + w3 * bf2f(r3.w);
        ds += w0 + w1 + w2 + w3;
    }
    for (; i < end; ++i) {
        unsigned e = eids[i];
        float w = ew[e];
        int s = nbr[e];
        ushort4 r = *(const ushort4*)(acw + (size_t)s * C + cb);
        a0 += w * bf2f(r.x);
        a1 += w * bf2f(r.y);
        a2 += w * bf2f(r.z);
        a3 += w * bf2f(r.w);
        ds += w;
    }
    float4 o = make_float4(a0, a1, a2, a3);
    *(float4*)(out + (size_t)v * C + cb) = o;
    if (lane == 0) deg[v] = ds;
}

// ---------- MFMA GEMM2 (gathered rows, dual B, fused epilogue) ----------
__global__ __launch_bounds__(256, 1)
void k_gemm_final(const ushort* __restrict__ Ab, const int* __restrict__ vnodes,
                  const ushort* __restrict__ W1t, const float* __restrict__ b1v,
                  const ushort* __restrict__ W2t, const float* __restrict__ b2v,
                  const float* __restrict__ deg, float* __restrict__ out, int V) {
    __shared__ __align__(16) ushort Al[128][40];
    __shared__ __align__(16) ushort B1l[128][40];
    __shared__ __align__(16) ushort B2l[128][40];
    const int tid = threadIdx.x;
    const int row0 = blockIdx.y * 128, col0 = blockIdx.x * 128;
    const int lane = tid & 63, wv = tid >> 6;
    const int wr = wv >> 1, wc = wv & 1;

    f32x4 acc1[4][4] = {}, acc2[4][4] = {};

    int grow[2];
#pragma unroll
    for (int i = 0; i < 2; ++i) {
        int idx = tid + 256 * i;
        int vr = row0 + (idx >> 2);
        grow[i] = (vr < V) ? vnodes[vr] : -1;
    }

    for (int k0 = 0; k0 < C; k0 += 32) {
#pragma unroll
        for (int i = 0; i < 2; ++i) {
            int idx = tid + 256 * i;
            int r = idx >> 2, ch = idx & 3;
            uint4 va = (grow[i] >= 0) ? *(const uint4*)(Ab + (size_t)grow[i] * C + k0 + ch * 8)
                                      : make_uint4(0, 0, 0, 0);
            *(uint4*)&Al[r][ch * 8] = va;
            *(uint4*)&B1l[r][ch * 8] = *(const uint4*)(W1t + (size_t)(col0 + r) * C + k0 + ch * 8);
            *(uint4*)&B2l[r][ch * 8] = *(const uint4*)(W2t + (size_t)(col0 + r) * C + k0 + ch * 8);
        }
        __syncthreads();
        bf16x8 af[4], b1f[4], b2f[4];
        const int kc = (lane >> 4) * 8;
#pragma unroll
        for (int m = 0; m < 4; ++m) af[m] = *(const bf16x8*)&Al[wr * 64 + m * 16 + (lane & 15)][kc];
#pragma unroll
        for (int n = 0; n < 4; ++n) {
            b1f[n] = *(const bf16x8*)&B1l[wc * 64 + n * 16 + (lane & 15)][kc];
            b2f[n] = *(const bf16x8*)&B2l[wc * 64 + n * 16 + (lane & 15)][kc];
        }
#pragma unroll
        for (int m = 0; m < 4; ++m)
#pragma unroll
            for (int n = 0; n < 4; ++n) {
                acc1[m][n] = __builtin_amdgcn_mfma_f32_16x16x32_bf16(af[m], b1f[n], acc1[m][n], 0, 0, 0);
                acc2[m][n] = __builtin_amdgcn_mfma_f32_16x16x32_bf16(af[m], b2f[n], acc2[m][n], 0, 0, 0);
            }
        __syncthreads();
    }

#pragma unroll
    for (int m = 0; m < 4; ++m) {
        int rbase = row0 + wr * 64 + m * 16 + (lane >> 4) * 4;
#pragma unroll
        for (int n = 0; n < 4; ++n) {
            int col = col0 + wc * 64 + n * 16 + (lane & 15);
            float bc1 = b1v[col], bc2 = b2v[col];
#pragma unroll
            for (int r = 0; r < 4; ++r) {
                int vr = rbase + r;
                if (vr < V) {
                    size_t o = (size_t)vr * C + col;
                    float d = deg[vr];
                    out[o] = out[o] + d * (acc1[m][n][r] + bc1) + acc2[m][n][r] + bc2;
                }
            }
        }
    }
}

extern "C" void kernel_launch(void* const* d_in, const int* in_sizes, int n_in,
                              void* d_out, int out_size, void* d_ws, size_t ws_size,
                              hipStream_t stream) {
    const float* A    = (const float*)d_in[0];
    const int* vnodes = (const int*)d_in[2];
    const int* index1 = (const int*)d_in[4];
    const int* nbr    = (const int*)d_in[5];
    const float* ew   = (const float*)d_in[9];
    const float* W_w  = (const float*)d_in[10];
    const float* b_w  = (const float*)d_in[11];
    const float* W1   = (const float*)d_in[12];
    const float* b1   = (const float*)d_in[13];
    const float* W2   = (const float*)d_in[14];
    const float* b2   = (const float*)d_in[15];
    float* out = (float*)d_out;

    const int N = in_sizes[0] / C;
    const int V = in_sizes[2];
    const int E = in_sizes[4];

    char* ws = (char*)d_ws;
    size_t off = 0;
    auto carve = [&](size_t bytes) -> void* {
        void* p = ws + off;
        off = (off + bytes + 255) & ~(size_t)255;
        return p;
    };
    ushort* Ab        = (ushort*)carve((size_t)N * C * sizeof(ushort));
    ushort* acw       = (ushort*)carve((size_t)N * C * sizeof(ushort));
    ushort* W_wt      = (ushort*)carve((size_t)C * C * sizeof(ushort));
    ushort* W1t       = (ushort*)carve((size_t)C * C * sizeof(ushort));
    ushort* W2t       = (ushort*)carve((size_t)C * C * sizeof(ushort));
    float* deg        = (float*)carve((size_t)V * sizeof(float));
    unsigned* count   = (unsigned*)carve((size_t)V * sizeof(unsigned));
    unsigned* offsets = (unsigned*)carve((size_t)(V + 1) * sizeof(unsigned));
    unsigned* cursor  = (unsigned*)carve((size_t)V * sizeof(unsigned));
    unsigned* eids    = (unsigned*)carve((size_t)E * sizeof(unsigned));

    hipMemsetAsync(count, 0, (size_t)V * sizeof(unsigned), stream);
    hipMemsetAsync(cursor, 0, (size_t)V * sizeof(unsigned), stream);

    const int n8 = N * C / 8;
    k_cast_a<<<(n8 + 255) / 256, 256, 0, stream>>>(A, Ab, n8);
    k_cast_wt<<<(3 * 65536) / 256, 256, 0, stream>>>(W_w, W_wt, W1, W1t, W2, W2t);
    k_gemm_acw<<<dim3(2, (N + 127) / 128), 256, 0, stream>>>(Ab, W_wt, b_w, acw, N);
    k_count<<<(E + 255) / 256, 256, 0, stream>>>(index1, count, E);
    k_scan<<<1, 1024, 0, stream>>>(count, offsets, V);
    k_fill<<<(E + 255) / 256, 256, 0, stream>>>(index1, offsets, cursor, eids, E);
    k_aggr<<<(V + 3) / 4, 256, 0, stream>>>(offsets, eids, ew, nbr, acw, out, deg, V);
    k_gemm_final<<<dim3(2, (V + 127) / 128), 256, 0, stream>>>(Ab, vnodes, W1t, b1, W2t, b2, deg, out, V);
}

// Round 9
// 567.322 us; speedup vs baseline: 1.9139x; 1.1990x over previous
//
#include <hip/hip_runtime.h>
#include <hip/hip_bf16.h>

#define C 256

typedef __attribute__((ext_vector_type(8))) short bf16x8;
typedef __attribute__((ext_vector_type(4))) float f32x4;

__device__ __forceinline__ ushort f2bf(float x) {
    unsigned u = __float_as_uint(x);
    unsigned r = (u + 0x7fffu + ((u >> 16) & 1u)) >> 16;
    return (ushort)r;
}
__device__ __forceinline__ float bf2f(ushort u) {
    return __uint_as_float((unsigned)u << 16);
}
__device__ __forceinline__ unsigned pack2(float lo, float hi) {
    return (unsigned)f2bf(lo) | ((unsigned)f2bf(hi) << 16);
}

// ---------- LDS-tiled transpose+cast: T[n][k] = bf16(W[k][n]), 3 matrices ----------
__global__ void k_cast_wt(const float* __restrict__ W0, ushort* __restrict__ T0,
                          const float* __restrict__ W1, ushort* __restrict__ T1,
                          const float* __restrict__ W2, ushort* __restrict__ T2) {
    __shared__ float t[64][65];
    const int which = blockIdx.x >> 4, tile = blockIdx.x & 15;
    const int k0 = (tile >> 2) * 64, n0 = (tile & 3) * 64;
    const float* W = (which == 0) ? W0 : (which == 1) ? W1 : W2;
    ushort* T = (which == 0) ? T0 : (which == 1) ? T1 : T2;
    const int tid = threadIdx.x;
    const int r = tid >> 2, cq = (tid & 3) * 16;
#pragma unroll
    for (int j = 0; j < 4; ++j) {
        float4 v = *(const float4*)(W + (size_t)(k0 + r) * C + n0 + cq + j * 4);
        t[r][cq + j * 4 + 0] = v.x;
        t[r][cq + j * 4 + 1] = v.y;
        t[r][cq + j * 4 + 2] = v.z;
        t[r][cq + j * 4 + 3] = v.w;
    }
    __syncthreads();
    // thread writes row n = tid>>2, k range cq..cq+15
    ushort o[16];
#pragma unroll
    for (int j = 0; j < 16; ++j) o[j] = f2bf(t[cq + j][r]);
    ushort* dst = T + (size_t)(n0 + r) * C + k0 + cq;
    *(uint4*)dst = *(const uint4*)&o[0];
    *(uint4*)(dst + 8) = *(const uint4*)&o[8];
}

// ---------- MFMA GEMM1: acw[M][256] = bf16( f32A @ W ) + bias, bf16 out ----------
__global__ __launch_bounds__(256, 2)
void k_gemm_acw(const float* __restrict__ A, const ushort* __restrict__ Wt,
                const float* __restrict__ bias, ushort* __restrict__ acw, int M) {
    __shared__ __align__(16) ushort Al[128][40];
    __shared__ __align__(16) ushort Bl[128][40];
    const int tid = threadIdx.x;
    const int row0 = blockIdx.y * 128, col0 = blockIdx.x * 128;
    const int lane = tid & 63, wv = tid >> 6;
    const int wr = wv >> 1, wc = wv & 1;

    f32x4 acc[4][4] = {};

    int arow[2];
#pragma unroll
    for (int i = 0; i < 2; ++i) arow[i] = row0 + ((tid + 256 * i) >> 2);

    for (int k0 = 0; k0 < C; k0 += 32) {
#pragma unroll
        for (int i = 0; i < 2; ++i) {
            int idx = tid + 256 * i;
            int r = idx >> 2, q = idx & 3;
            uint4 o = make_uint4(0, 0, 0, 0);
            if (arow[i] < M) {
                const float* src = A + (size_t)arow[i] * C + k0 + q * 8;
                float4 a = *(const float4*)src;
                float4 b = *(const float4*)(src + 4);
                o.x = pack2(a.x, a.y);
                o.y = pack2(a.z, a.w);
                o.z = pack2(b.x, b.y);
                o.w = pack2(b.z, b.w);
            }
            *(uint4*)&Al[r][q * 8] = o;
            *(uint4*)&Bl[r][q * 8] = *(const uint4*)(Wt + (size_t)(col0 + r) * C + k0 + q * 8);
        }
        __syncthreads();
        bf16x8 af[4], bfr[4];
        const int kc = (lane >> 4) * 8;
#pragma unroll
        for (int m = 0; m < 4; ++m) af[m] = *(const bf16x8*)&Al[wr * 64 + m * 16 + (lane & 15)][kc];
#pragma unroll
        for (int n = 0; n < 4; ++n) bfr[n] = *(const bf16x8*)&Bl[wc * 64 + n * 16 + (lane & 15)][kc];
#pragma unroll
        for (int m = 0; m < 4; ++m)
#pragma unroll
            for (int n = 0; n < 4; ++n)
                acc[m][n] = __builtin_amdgcn_mfma_f32_16x16x32_bf16(af[m], bfr[n], acc[m][n], 0, 0, 0);
        __syncthreads();
    }

#pragma unroll
    for (int m = 0; m < 4; ++m) {
        int rbase = row0 + wr * 64 + m * 16 + (lane >> 4) * 4;
#pragma unroll
        for (int n = 0; n < 4; ++n) {
            int col = col0 + wc * 64 + n * 16 + (lane & 15);
            float bc = bias[col];
#pragma unroll
            for (int r = 0; r < 4; ++r) {
                int gr = rbase + r;
                if (gr < M) acw[(size_t)gr * C + col] = f2bf(acc[m][n][r] + bc);
            }
        }
    }
}

// ---------- CSR build ----------
__global__ void k_count(const int* __restrict__ index1, unsigned* __restrict__ count, int E) {
    int e = blockIdx.x * blockDim.x + threadIdx.x;
    if (e < E) atomicAdd(&count[index1[e]], 1u);
}

__global__ void k_scanA(const unsigned* __restrict__ count, unsigned* __restrict__ offsets,
                        unsigned* __restrict__ part, int V) {
    __shared__ unsigned s[1024];
    const int tid = threadIdx.x;
    const int i = blockIdx.x * 1024 + tid;
    unsigned x = (i < V) ? count[i] : 0u;
    s[tid] = x;
    __syncthreads();
    for (int off = 1; off < 1024; off <<= 1) {
        unsigned t = (tid >= off) ? s[tid - off] : 0u;
        __syncthreads();
        s[tid] += t;
        __syncthreads();
    }
    if (i < V) offsets[i] = s[tid] - x;
    if (tid == 1023) part[blockIdx.x] = s[1023];
}

__global__ void k_scanB(unsigned* __restrict__ part, unsigned* __restrict__ offsets, int nPart, int V) {
    const int lane = threadIdx.x;
    unsigned orig = (lane < nPart) ? part[lane] : 0u;
    unsigned x = orig;
    for (int off = 1; off < 64; off <<= 1) {
        unsigned t = __shfl_up(x, off);
        if (lane >= off) x += t;
    }
    if (lane < nPart) part[lane] = x - orig;
    unsigned tot = __shfl(x, nPart - 1);
    if (lane == 0) offsets[V] = tot;
}

__global__ void k_scanC(unsigned* __restrict__ offsets, const unsigned* __restrict__ part, int V) {
    int i = blockIdx.x * 1024 + threadIdx.x;
    if (i < V) offsets[i] += part[blockIdx.x];
}

// ---------- fill: CSR payload = (nbr, edge_weight) pairs ----------
__global__ void k_fill(const int* __restrict__ index1, const int* __restrict__ nbr,
                       const float* __restrict__ ew, const unsigned* __restrict__ offsets,
                       unsigned* __restrict__ cursor, uint2* __restrict__ edata, int E) {
    int e = blockIdx.x * blockDim.x + threadIdx.x;
    if (e < E) {
        int v = index1[e];
        unsigned pos = atomicAdd(&cursor[v], 1u);
        edata[offsets[v] + pos] = make_uint2((unsigned)nbr[e], __float_as_uint(ew[e]));
    }
}

// ---------- aggregation: wave per node, lane holds 4 channels, 8 edges in flight ----------
__global__ void k_aggr(const unsigned* __restrict__ offsets, const uint2* __restrict__ edata,
                       const ushort* __restrict__ acw, float* __restrict__ out,
                       float* __restrict__ deg, int V) {
    const int v = (blockIdx.x * blockDim.x + threadIdx.x) >> 6;
    const int lane = threadIdx.x & 63;
    if (v >= V) return;
    const unsigned beg = offsets[v], end = offsets[v + 1];
    const int cb = lane * 4;
    float a0 = 0.f, a1 = 0.f, a2 = 0.f, a3 = 0.f, ds = 0.f;
    unsigned i = beg;
    for (; i + 8 <= end; i += 8) {
        uint2 p[8];
#pragma unroll
        for (int j = 0; j < 8; ++j) p[j] = edata[i + j];
        ushort4 r[8];
#pragma unroll
        for (int j = 0; j < 8; ++j) r[j] = *(const ushort4*)(acw + (size_t)p[j].x * C + cb);
#pragma unroll
        for (int j = 0; j < 8; ++j) {
            float w = __uint_as_float(p[j].y);
            a0 += w * bf2f(r[j].x);
            a1 += w * bf2f(r[j].y);
            a2 += w * bf2f(r[j].z);
            a3 += w * bf2f(r[j].w);
            ds += w;
        }
    }
    for (; i < end; ++i) {
        uint2 p = edata[i];
        float w = __uint_as_float(p.y);
        ushort4 r = *(const ushort4*)(acw + (size_t)p.x * C + cb);
        a0 += w * bf2f(r.x);
        a1 += w * bf2f(r.y);
        a2 += w * bf2f(r.z);
        a3 += w * bf2f(r.w);
        ds += w;
    }
    *(float4*)(out + (size_t)v * C + cb) = make_float4(a0, a1, a2, a3);
    if (lane == 0) deg[v] = ds;
}

// ---------- MFMA GEMM2 (gathered f32 rows, dual B, fused epilogue) ----------
__global__ __launch_bounds__(256, 1)
void k_gemm_final(const float* __restrict__ A, const int* __restrict__ vnodes,
                  const ushort* __restrict__ W1t, const float* __restrict__ b1v,
                  const ushort* __restrict__ W2t, const float* __restrict__ b2v,
                  const float* __restrict__ deg, float* __restrict__ out, int V) {
    __shared__ __align__(16) ushort Al[128][40];
    __shared__ __align__(16) ushort B1l[128][40];
    __shared__ __align__(16) ushort B2l[128][40];
    const int tid = threadIdx.x;
    const int row0 = blockIdx.y * 128, col0 = blockIdx.x * 128;
    const int lane = tid & 63, wv = tid >> 6;
    const int wr = wv >> 1, wc = wv & 1;

    f32x4 acc1[4][4] = {}, acc2[4][4] = {};

    int grow[2];
#pragma unroll
    for (int i = 0; i < 2; ++i) {
        int vr = row0 + ((tid + 256 * i) >> 2);
        grow[i] = (vr < V) ? vnodes[vr] : -1;
    }

    for (int k0 = 0; k0 < C; k0 += 32) {
#pragma unroll
        for (int i = 0; i < 2; ++i) {
            int idx = tid + 256 * i;
            int r = idx >> 2, q = idx & 3;
            uint4 o = make_uint4(0, 0, 0, 0);
            if (grow[i] >= 0) {
                const float* src = A + (size_t)grow[i] * C + k0 + q * 8;
                float4 a = *(const float4*)src;
                float4 b = *(const float4*)(src + 4);
                o.x = pack2(a.x, a.y);
                o.y = pack2(a.z, a.w);
                o.z = pack2(b.x, b.y);
                o.w = pack2(b.z, b.w);
            }
            *(uint4*)&Al[r][q * 8] = o;
            *(uint4*)&B1l[r][q * 8] = *(const uint4*)(W1t + (size_t)(col0 + r) * C + k0 + q * 8);
            *(uint4*)&B2l[r][q * 8] = *(const uint4*)(W2t + (size_t)(col0 + r) * C + k0 + q * 8);
        }
        __syncthreads();
        bf16x8 af[4], b1f[4], b2f[4];
        const int kc = (lane >> 4) * 8;
#pragma unroll
        for (int m = 0; m < 4; ++m) af[m] = *(const bf16x8*)&Al[wr * 64 + m * 16 + (lane & 15)][kc];
#pragma unroll
        for (int n = 0; n < 4; ++n) {
            b1f[n] = *(const bf16x8*)&B1l[wc * 64 + n * 16 + (lane & 15)][kc];
            b2f[n] = *(const bf16x8*)&B2l[wc * 64 + n * 16 + (lane & 15)][kc];
        }
#pragma unroll
        for (int m = 0; m < 4; ++m)
#pragma unroll
            for (int n = 0; n < 4; ++n) {
                acc1[m][n] = __builtin_amdgcn_mfma_f32_16x16x32_bf16(af[m], b1f[n], acc1[m][n], 0, 0, 0);
                acc2[m][n] = __builtin_amdgcn_mfma_f32_16x16x32_bf16(af[m], b2f[n], acc2[m][n], 0, 0, 0);
            }
        __syncthreads();
    }

#pragma unroll
    for (int m = 0; m < 4; ++m) {
        int rbase = row0 + wr * 64 + m * 16 + (lane >> 4) * 4;
#pragma unroll
        for (int n = 0; n < 4; ++n) {
            int col = col0 + wc * 64 + n * 16 + (lane & 15);
            float bc1 = b1v[col], bc2 = b2v[col];
#pragma unroll
            for (int r = 0; r < 4; ++r) {
                int vr = rbase + r;
                if (vr < V) {
                    size_t o = (size_t)vr * C + col;
                    float d = deg[vr];
                    out[o] = out[o] + d * (acc1[m][n][r] + bc1) + acc2[m][n][r] + bc2;
                }
            }
        }
    }
}

extern "C" void kernel_launch(void* const* d_in, const int* in_sizes, int n_in,
                              void* d_out, int out_size, void* d_ws, size_t ws_size,
                              hipStream_t stream) {
    const float* A    = (const float*)d_in[0];
    const int* vnodes = (const int*)d_in[2];
    const int* index1 = (const int*)d_in[4];
    const int* nbr    = (const int*)d_in[5];
    const float* ew   = (const float*)d_in[9];
    const float* W_w  = (const float*)d_in[10];
    const float* b_w  = (const float*)d_in[11];
    const float* W1   = (const float*)d_in[12];
    const float* b1   = (const float*)d_in[13];
    const float* W2   = (const float*)d_in[14];
    const float* b2   = (const float*)d_in[15];
    float* out = (float*)d_out;

    const int N = in_sizes[0] / C;
    const int V = in_sizes[2];
    const int E = in_sizes[4];

    char* ws = (char*)d_ws;
    size_t off = 0;
    auto carve = [&](size_t bytes) -> void* {
        void* p = ws + off;
        off = (off + bytes + 255) & ~(size_t)255;
        return p;
    };
    ushort* acw       = (ushort*)carve((size_t)N * C * sizeof(ushort));
    ushort* W_wt      = (ushort*)carve((size_t)C * C * sizeof(ushort));
    ushort* W1t       = (ushort*)carve((size_t)C * C * sizeof(ushort));
    ushort* W2t       = (ushort*)carve((size_t)C * C * sizeof(ushort));
    float* deg        = (float*)carve((size_t)V * sizeof(float));
    unsigned* count   = (unsigned*)carve((size_t)V * sizeof(unsigned));
    unsigned* offsets = (unsigned*)carve((size_t)(V + 1) * sizeof(unsigned));
    unsigned* cursor  = (unsigned*)carve((size_t)V * sizeof(unsigned));
    unsigned* part    = (unsigned*)carve(64 * sizeof(unsigned));
    uint2* edata      = (uint2*)carve((size_t)E * sizeof(uint2));

    hipMemsetAsync(count, 0, (size_t)V * sizeof(unsigned), stream);
    hipMemsetAsync(cursor, 0, (size_t)V * sizeof(unsigned), stream);

    const int nPart = (V + 1023) / 1024;

    k_cast_wt<<<48, 256, 0, stream>>>(W_w, W_wt, W1, W1t, W2, W2t);
    k_gemm_acw<<<dim3(2, (N + 127) / 128), 256, 0, stream>>>(A, W_wt, b_w, acw, N);
    k_count<<<(E + 255) / 256, 256, 0, stream>>>(index1, count, E);
    k_scanA<<<nPart, 1024, 0, stream>>>(count, offsets, part, V);
    k_scanB<<<1, 64, 0, stream>>>(part, offsets, nPart, V);
    k_scanC<<<nPart, 1024, 0, stream>>>(offsets, part, V);
    k_fill<<<(E + 255) / 256, 256, 0, stream>>>(index1, nbr, ew, offsets, cursor, edata, E);
    k_aggr<<<(V + 3) / 4, 256, 0, stream>>>(offsets, edata, acw, out, deg, V);
    k_gemm_final<<<dim3(2, (V + 127) / 128), 256, 0, stream>>>(A, vnodes, W1t, b1, W2t, b2, deg, out, V);
}